// Round 1
// baseline (196.986 us; speedup 1.0000x reference)
//
#include <hip/hip_runtime.h>

#define LSIZE 24
#define VOL (LSIZE*LSIZE*LSIZE*LSIZE)       // 331776 sites
#define NLINES (LSIZE*LSIZE*LSIZE)          // 13824 lines per direction
#define CHUNK 3                             // links per thread
#define TPL 8                               // threads per line (scan width)
#define LPB 32                              // lines per block (4 waves * 8 lines)
#define TPB 256                             // 4 waves, no __syncthreads anywhere

// (o_re,o_im) = a * b, complex 3x3 matmul (row-major)
__device__ __forceinline__ void cmul(const float* __restrict__ ar, const float* __restrict__ ai,
                                     const float* __restrict__ br, const float* __restrict__ bi,
                                     float* __restrict__ or_, float* __restrict__ oi_) {
#pragma unroll
  for (int i = 0; i < 3; ++i) {
#pragma unroll
    for (int j = 0; j < 3; ++j) {
      float sr = 0.f, si = 0.f;
#pragma unroll
      for (int m = 0; m < 3; ++m) {
        float x = ar[i*3+m], y = ai[i*3+m];
        float u = br[m*3+j], v = bi[m*3+j];
        sr = fmaf(x, u, sr);
        sr = fmaf(-y, v, sr);
        si = fmaf(x, v, si);
        si = fmaf(y, u, si);
      }
      or_[i*3+j] = sr;
      oi_[i*3+j] = si;
    }
  }
}

__device__ __forceinline__ void cp9(float* dr, float* di, const float* sr, const float* si) {
#pragma unroll
  for (int e = 0; e < 9; ++e) { dr[e] = sr[e]; di[e] = si[e]; }
}

__device__ __forceinline__ void setid(float* r, float* im) {
#pragma unroll
  for (int e = 0; e < 9; ++e) { r[e] = (e == 0 || e == 4 || e == 8) ? 1.f : 0.f; im[e] = 0.f; }
}

// whole-matrix wave shuffles (18 x ds_bpermute each, no LDS storage, no barrier)
__device__ __forceinline__ void shup(float* dr, float* di, const float* sr, const float* si, int delta) {
#pragma unroll
  for (int e = 0; e < 9; ++e) {
    dr[e] = __shfl_up(sr[e], (unsigned)delta, 64);
    di[e] = __shfl_up(si[e], (unsigned)delta, 64);
  }
}
__device__ __forceinline__ void shdn(float* dr, float* di, const float* sr, const float* si, int delta) {
#pragma unroll
  for (int e = 0; e < 9; ++e) {
    dr[e] = __shfl_down(sr[e], (unsigned)delta, 64);
    di[e] = __shfl_down(si[e], (unsigned)delta, 64);
  }
}

// Chunked cyclic scan: thread t of a line owns links k = 3t..3t+2.
//   locA_j = U_{3t}..U_{3t+j}, locS_j = U_{3t+j}..U_{3t+2}, B = chunk product.
//   Wave-level exclusive prefix/suffix scans over the 8 chunk products give
//   preA_t = B_0..B_{t-1}, sufS_{t+1} = B_{t+1}..B_7;  R_t = sufS_{t+1} * preA_t.
//   P(3t+j) = locS_j * R_t * locA_{j-1}   (A_{-1} = I)
// All communication is intra-wave __shfl: zero LDS, zero __syncthreads.
__global__ __launch_bounds__(TPB, 2) void polyakov_chunk(
    const float* __restrict__ U_re, const float* __restrict__ U_im,
    float* __restrict__ out) {
  const int lane = threadIdx.x & 63;
  const int wv   = threadIdx.x >> 6;
  const int lineBase = blockIdx.x * LPB + wv * (64 / TPL);
  const int mu = lineBase / NLINES;          // block-uniform: 13824 % 32 == 0

  // Lane mapping keeps global loads coalesced for every direction:
  //  mu != 3: lines run along a far stride; put adjacent lines (x3) in adjacent
  //           lanes -> scan partners are 8 lanes apart.
  //  mu == 3: lines run along x3 (contiguous); put scan index in the low bits
  //           so each thread reads 216 contiguous bytes -> scan stride 1.
  int tl, ll, sh;
  if (mu == 3) { tl = lane & 7; ll = lane >> 3; sh = 1; }
  else         { tl = lane >> 3; ll = lane & 7; sh = 8; }

  const int L  = lineBase + ll;
  const int l  = L - mu * NLINES;
  const int cC = l % LSIZE;
  const int cB = (l / LSIZE) % LSIZE;
  const int cA = l / (LSIZE*LSIZE);

  int x0, x1, x2, x3, st;
  if (mu == 0)      { x0 = 0;  x1 = cA; x2 = cB; x3 = cC; st = LSIZE*LSIZE*LSIZE; }
  else if (mu == 1) { x0 = cA; x1 = 0;  x2 = cB; x3 = cC; st = LSIZE*LSIZE; }
  else if (mu == 2) { x0 = cA; x1 = cB; x2 = 0;  x3 = cC; st = LSIZE; }
  else              { x0 = cA; x1 = cB; x2 = cC; x3 = 0;  st = 1; }
  const int s0 = ((x0*LSIZE + x1)*LSIZE + x2)*LSIZE + x3;
  const int k0 = tl * CHUNK;

  const float* __restrict__ bR = U_re + (size_t)mu * (VOL*9);
  const float* __restrict__ bI = U_im + (size_t)mu * (VOL*9);

  // ---- load the 3 owned links ----
  float U0r[9], U0i[9], U1r[9], U1i[9], U2r[9], U2i[9];
  {
    const float* p = bR + (size_t)(s0 + (k0+0)*st) * 9;
    const float* q = bI + (size_t)(s0 + (k0+0)*st) * 9;
#pragma unroll
    for (int e = 0; e < 9; ++e) { U0r[e] = p[e]; U0i[e] = q[e]; }
  }
  {
    const float* p = bR + (size_t)(s0 + (k0+1)*st) * 9;
    const float* q = bI + (size_t)(s0 + (k0+1)*st) * 9;
#pragma unroll
    for (int e = 0; e < 9; ++e) { U1r[e] = p[e]; U1i[e] = q[e]; }
  }
  {
    const float* p = bR + (size_t)(s0 + (k0+2)*st) * 9;
    const float* q = bI + (size_t)(s0 + (k0+2)*st) * 9;
#pragma unroll
    for (int e = 0; e < 9; ++e) { U2r[e] = p[e]; U2i[e] = q[e]; }
  }

  // ---- local chunk products (U1 dies after this) ----
  float A1r[9], A1i[9], Br[9], Bi[9], S1r[9], S1i[9];
  cmul(U0r, U0i, U1r, U1i, A1r, A1i);   // A1 = U0*U1
  cmul(A1r, A1i, U2r, U2i, Br,  Bi);    // B  = U0*U1*U2
  cmul(U1r, U1i, U2r, U2i, S1r, S1i);   // S1 = U1*U2
  // locA0 = U0, locS2 = U2, locS0 = B

  float Tr[9], Ti[9], Yr[9], Yi[9];

  // ---- inclusive prefix scan of B over 8 threads (3 shuffle steps) ----
  float Xr[9], Xi[9];
  cp9(Xr, Xi, Br, Bi);
#pragma unroll
  for (int d = 1; d < TPL; d <<= 1) {
    shup(Yr, Yi, Xr, Xi, d * sh);
    if (tl >= d) { cmul(Yr, Yi, Xr, Xi, Tr, Ti); cp9(Xr, Xi, Tr, Ti); }
  }

  // ---- inclusive suffix scan of B (3 shuffle steps) ----
  float Zr[9], Zi[9];
  cp9(Zr, Zi, Br, Bi);
#pragma unroll
  for (int d = 1; d < TPL; d <<= 1) {
    shdn(Yr, Yi, Zr, Zi, d * sh);
    if (tl + d < TPL) { cmul(Zr, Zi, Yr, Yi, Tr, Ti); cp9(Zr, Zi, Tr, Ti); }
  }

  // ---- exclusive ends + complement product R ----
  float Pr[9], Pi[9], Qr[9], Qi[9];
  shup(Pr, Pi, Xr, Xi, sh);            // preA_t = incA_{t-1}
  if (tl == 0) setid(Pr, Pi);
  shdn(Qr, Qi, Zr, Zi, sh);            // sufS_{t+1} = incS_{t+1}
  if (tl == TPL - 1) setid(Qr, Qi);

  float Rr[9], Ri[9];
  cmul(Qr, Qi, Pr, Pi, Rr, Ri);        // R = (B_{t+1}..B_7)*(B_0..B_{t-1})

  // ---- outputs: P(3t+j) = locS_j * R * locA_{j-1} ----
  float* oR = out + (size_t)mu * (VOL*9);
  float* oI = out + (size_t)(4 + mu) * (VOL*9);
  float Wr[9], Wi[9];

  // j = 0: P = B * R
  cmul(Br, Bi, Rr, Ri, Tr, Ti);
  {
    float* pr = oR + (size_t)(s0 + (k0+0)*st) * 9;
    float* pi = oI + (size_t)(s0 + (k0+0)*st) * 9;
#pragma unroll
    for (int e = 0; e < 9; ++e) { pr[e] = Tr[e]; pi[e] = Ti[e]; }
  }
  // j = 1: P = S1 * (R * U0)
  cmul(Rr, Ri, U0r, U0i, Tr, Ti);
  cmul(S1r, S1i, Tr, Ti, Wr, Wi);
  {
    float* pr = oR + (size_t)(s0 + (k0+1)*st) * 9;
    float* pi = oI + (size_t)(s0 + (k0+1)*st) * 9;
#pragma unroll
    for (int e = 0; e < 9; ++e) { pr[e] = Wr[e]; pi[e] = Wi[e]; }
  }
  // j = 2: P = U2 * (R * A1)
  cmul(Rr, Ri, A1r, A1i, Tr, Ti);
  cmul(U2r, U2i, Tr, Ti, Wr, Wi);
  {
    float* pr = oR + (size_t)(s0 + (k0+2)*st) * 9;
    float* pi = oI + (size_t)(s0 + (k0+2)*st) * 9;
#pragma unroll
    for (int e = 0; e < 9; ++e) { pr[e] = Wr[e]; pi[e] = Wi[e]; }
  }
}

extern "C" void kernel_launch(void* const* d_in, const int* in_sizes, int n_in,
                              void* d_out, int out_size, void* d_ws, size_t ws_size,
                              hipStream_t stream) {
  const float* U_re = (const float*)d_in[0];
  const float* U_im = (const float*)d_in[1];
  float* out = (float*)d_out;
  int nblocks = 4 * NLINES / LPB;   // 1728 blocks x 256 threads
  hipLaunchKernelGGL(polyakov_chunk, dim3(nblocks), dim3(TPB), 0, stream, U_re, U_im, out);
}

// Round 2
// 182.874 us; speedup vs baseline: 1.0772x; 1.0772x over previous
//
#include <hip/hip_runtime.h>

#define LSIZE 24
#define VOL (LSIZE*LSIZE*LSIZE*LSIZE)       // 331776 sites
#define NLINES (LSIZE*LSIZE*LSIZE)          // 13824 lines per direction
#define LPB 16                              // lines per block
#define TPB 128                             // 2 waves
#define SLABSTRIDE (LPB*9 + 1)              // 145 dwords (pad -> 2-way banks, free)
#define ARRSTRIDE (LSIZE*SLABSTRIDE)        // 3480 dwords per re/im array

// (o_re,o_im) = a * b, complex 3x3 matmul (row-major). Output must not alias inputs.
__device__ __forceinline__ void cmul(const float* __restrict__ ar, const float* __restrict__ ai,
                                     const float* __restrict__ br, const float* __restrict__ bi,
                                     float* __restrict__ or_, float* __restrict__ oi_) {
#pragma unroll
  for (int i = 0; i < 3; ++i) {
#pragma unroll
    for (int j = 0; j < 3; ++j) {
      float sr = 0.f, si = 0.f;
#pragma unroll
      for (int m = 0; m < 3; ++m) {
        float x = ar[i*3+m], y = ai[i*3+m];
        float u = br[m*3+j], v = bi[m*3+j];
        sr = fmaf(x, u, sr);
        sr = fmaf(-y, v, sr);
        si = fmaf(x, v, si);
        si = fmaf(y, u, si);
      }
      or_[i*3+j] = sr;
      oi_[i*3+j] = si;
    }
  }
}

__device__ __forceinline__ void cp9(float* dr, float* di, const float* sr, const float* si) {
#pragma unroll
  for (int e = 0; e < 9; ++e) { dr[e] = sr[e]; di[e] = si[e]; }
}

__device__ __forceinline__ void setid(float* r, float* im) {
#pragma unroll
  for (int e = 0; e < 9; ++e) { r[e] = (e == 0 || e == 4 || e == 8) ? 1.f : 0.f; im[e] = 0.f; }
}

__device__ __forceinline__ void ldm9(const float* __restrict__ L, float* v) {
#pragma unroll
  for (int e = 0; e < 9; ++e) v[e] = L[e];
}
__device__ __forceinline__ void stm9(float* __restrict__ L, const float* v) {
#pragma unroll
  for (int e = 0; e < 9; ++e) L[e] = v[e];
}

// whole-matrix intra-wave gather via ds_bpermute; one addr shared by 18 elements.
__device__ __forceinline__ void bperm9x2(float* dr, float* di,
                                         const float* sr, const float* si, int srclane) {
  int a = (srclane & 63) << 2;
#pragma unroll
  for (int e = 0; e < 9; ++e) {
    dr[e] = __int_as_float(__builtin_amdgcn_ds_bpermute(a, __float_as_int(sr[e])));
    di[e] = __int_as_float(__builtin_amdgcn_ds_bpermute(a, __float_as_int(si[e])));
  }
}

// Block = 16 lines x 24 slabs staged in LDS.
//   stage-in  : coalesced global -> LDS (unit = one 9-float matrix half)
//   compute   : per line, 8 threads x 3-link chunks; in-wave scan of chunk
//               products via ds_bpermute; P(3t+j) = locS_j * R_t * locA_{j-1};
//               results written back to the same LDS slots (each slot touched
//               by exactly one thread -> in-place safe)
//   stage-out : coalesced LDS -> global
__global__ __launch_bounds__(TPB, 2) void polyakov_staged(
    const float* __restrict__ U_re, const float* __restrict__ U_im,
    float* __restrict__ out) {
  __shared__ float lds[2 * ARRSTRIDE];   // 27840 B

  const int t = threadIdx.x;
  const int lane = t & 63;
  const int w = t >> 6;

  const int Lb = blockIdx.x * LPB;       // global line base
  const int mu = Lb / NLINES;            // block-uniform (13824 % 16 == 0)
  const int l0 = Lb - mu * NLINES;

  // site(l,k) = cA*e0 + cB*e1 + cC*e2 + k*st, with l = cA*576 + cB*24 + cC
  int st, e0, e1, e2;
  if (mu == 0)      { st = 13824; e0 = 576;   e1 = 24;  e2 = 1;  }
  else if (mu == 1) { st = 576;   e0 = 13824; e1 = 24;  e2 = 1;  }
  else if (mu == 2) { st = 24;    e0 = 13824; e1 = 576; e2 = 1;  }
  else              { st = 1;     e0 = 13824; e1 = 576; e2 = 24; }

  const float* __restrict__ gR = U_re + (size_t)mu * (VOL*9);
  const float* __restrict__ gI = U_im + (size_t)mu * (VOL*9);

  // ---------------- stage in ----------------
  if (mu != 3) {
    // unit order: line fast (lines are site-contiguous for mu=0/1, 24-runs for mu=2)
#pragma unroll
    for (int p = 0; p < 6; ++p) {
      int u = p * TPB + t;              // [0, 768)
      int slab = u >> 5;
      int r = u & 31;
      int arr = r >> 4;
      int line = r & 15;
      int l = l0 + line;
      int cC = l % LSIZE; int q = l / LSIZE; int cB = q % LSIZE; int cA = q / LSIZE;
      int site = cA*e0 + cB*e1 + cC*e2 + slab * st;
      const float* g = (arr ? gI : gR) + (size_t)site * 9;
      float* L = lds + arr*ARRSTRIDE + slab*SLABSTRIDE + line*9;
#pragma unroll
      for (int e = 0; e < 9; ++e) L[e] = g[e];
    }
  } else {
    // mu==3: lines are contiguous along the line axis -> k fast (864B runs)
#pragma unroll
    for (int p = 0; p < 6; ++p) {
      int u = p * TPB + t;
      int line = u / 48;
      int r = u - 48 * line;
      int arr = r / 24;
      int k = r - 24 * arr;
      int site = (l0 + line) * 24 + k;
      const float* g = (arr ? gI : gR) + (size_t)site * 9;
      float* L = lds + arr*ARRSTRIDE + k*SLABSTRIDE + line*9;
#pragma unroll
      for (int e = 0; e < 9; ++e) L[e] = g[e];
    }
  }
  __syncthreads();

  // ---------------- compute ----------------
  const int tl = lane >> 3;              // chunk index along line, 0..7
  const int ll = lane & 7;               // line within wave's octet
  const int line_b = w * 8 + ll;         // 0..15
  const int k0 = 3 * tl;

  float* mR = lds + line_b * 9;
  float* mI = lds + ARRSTRIDE + line_b * 9;

  float Xr[9], Xi[9], Zr[9], Zi[9], Yr[9], Yi[9], Tr[9], Ti[9], Rr[9], Ri[9];

  // B = U0*U1*U2 (U's not kept live)
  ldm9(mR + (k0+0)*SLABSTRIDE, Xr); ldm9(mI + (k0+0)*SLABSTRIDE, Xi);   // U0
  ldm9(mR + (k0+1)*SLABSTRIDE, Yr); ldm9(mI + (k0+1)*SLABSTRIDE, Yi);   // U1
  cmul(Xr, Xi, Yr, Yi, Tr, Ti);                                        // T = U0*U1
  ldm9(mR + (k0+2)*SLABSTRIDE, Yr); ldm9(mI + (k0+2)*SLABSTRIDE, Yi);   // U2
  cmul(Tr, Ti, Yr, Yi, Zr, Zi);                                        // Z = B
  cp9(Xr, Xi, Zr, Zi);                                                 // X = B

  // inclusive prefix scan (X_t = B_0..B_t)
#pragma unroll
  for (int d = 1; d < 8; d <<= 1) {
    bperm9x2(Yr, Yi, Xr, Xi, lane - 8*d);
    if (tl >= d) { cmul(Yr, Yi, Xr, Xi, Tr, Ti); cp9(Xr, Xi, Tr, Ti); }
  }
  // inclusive suffix scan (Z_t = B_t..B_7)
#pragma unroll
  for (int d = 1; d < 8; d <<= 1) {
    bperm9x2(Yr, Yi, Zr, Zi, lane + 8*d);
    if (tl + d < 8) { cmul(Zr, Zi, Yr, Yi, Tr, Ti); cp9(Zr, Zi, Tr, Ti); }
  }

  // R = sufS_{t+1} * preA_t
  bperm9x2(Tr, Ti, Zr, Zi, lane + 8);    // Q = Z[t+1]
  if (tl == 7) setid(Tr, Ti);
  bperm9x2(Yr, Yi, Xr, Xi, lane - 8);    // P = X[t-1]
  if (tl == 0) setid(Yr, Yi);
  cmul(Tr, Ti, Yr, Yi, Rr, Ri);          // R

  // outputs via W-chain; reload U's from LDS (all reloads precede all writes)
  ldm9(mR + (k0+2)*SLABSTRIDE, Yr); ldm9(mI + (k0+2)*SLABSTRIDE, Yi);   // U2
  cmul(Yr, Yi, Rr, Ri, Tr, Ti);                                        // T = W2 = U2*R
  ldm9(mR + (k0+1)*SLABSTRIDE, Xr); ldm9(mI + (k0+1)*SLABSTRIDE, Xi);   // X = U1 (kept)
  cmul(Xr, Xi, Tr, Ti, Zr, Zi);                                        // Z = W1 = U1*W2
  ldm9(mR + (k0+0)*SLABSTRIDE, Yr); ldm9(mI + (k0+0)*SLABSTRIDE, Yi);   // Y = U0 (kept)

  cmul(Yr, Yi, Zr, Zi, Rr, Ri);          // out0 = U0*W1   (R dead -> reuse)
  stm9(mR + (k0+0)*SLABSTRIDE, Rr); stm9(mI + (k0+0)*SLABSTRIDE, Ri);
  cmul(Zr, Zi, Yr, Yi, Rr, Ri);          // out1 = W1*U0
  stm9(mR + (k0+1)*SLABSTRIDE, Rr); stm9(mI + (k0+1)*SLABSTRIDE, Ri);
  cmul(Tr, Ti, Yr, Yi, Zr, Zi);          // Z = V = W2*U0  (W1 dead)
  cmul(Zr, Zi, Xr, Xi, Rr, Ri);          // out2 = V*U1
  stm9(mR + (k0+2)*SLABSTRIDE, Rr); stm9(mI + (k0+2)*SLABSTRIDE, Ri);

  __syncthreads();

  // ---------------- stage out ----------------
  float* __restrict__ oRg = out + (size_t)mu * (VOL*9);
  float* __restrict__ oIg = out + (size_t)(4 + mu) * (VOL*9);

  if (mu != 3) {
#pragma unroll
    for (int p = 0; p < 6; ++p) {
      int u = p * TPB + t;
      int slab = u >> 5;
      int r = u & 31;
      int arr = r >> 4;
      int line = r & 15;
      int l = l0 + line;
      int cC = l % LSIZE; int q = l / LSIZE; int cB = q % LSIZE; int cA = q / LSIZE;
      int site = cA*e0 + cB*e1 + cC*e2 + slab * st;
      float* g = (arr ? oIg : oRg) + (size_t)site * 9;
      const float* L = lds + arr*ARRSTRIDE + slab*SLABSTRIDE + line*9;
#pragma unroll
      for (int e = 0; e < 9; ++e) g[e] = L[e];
    }
  } else {
#pragma unroll
    for (int p = 0; p < 6; ++p) {
      int u = p * TPB + t;
      int line = u / 48;
      int r = u - 48 * line;
      int arr = r / 24;
      int k = r - 24 * arr;
      int site = (l0 + line) * 24 + k;
      float* g = (arr ? oIg : oRg) + (size_t)site * 9;
      const float* L = lds + arr*ARRSTRIDE + k*SLABSTRIDE + line*9;
#pragma unroll
      for (int e = 0; e < 9; ++e) g[e] = L[e];
    }
  }
}

extern "C" void kernel_launch(void* const* d_in, const int* in_sizes, int n_in,
                              void* d_out, int out_size, void* d_ws, size_t ws_size,
                              hipStream_t stream) {
  const float* U_re = (const float*)d_in[0];
  const float* U_im = (const float*)d_in[1];
  float* out = (float*)d_out;
  int nblocks = 4 * NLINES / LPB;   // 3456 blocks x 128 threads
  hipLaunchKernelGGL(polyakov_staged, dim3(nblocks), dim3(TPB), 0, stream, U_re, U_im, out);
}